// Round 1
// baseline (1042.871 us; speedup 1.0000x reference)
//
#include <hip/hip_runtime.h>
#include <math.h>

#define BB 64
#define CC 1024
#define QQ 256
#define DD 128
#define NEGV (-1.0e30f)

// ---------------- k0: s0 = xc@W0, s1 = xq@W1, xqw = xq*W2 ----------------
__global__ __launch_bounds__(256) void k0_pre(const float* __restrict__ xc,
                                              const float* __restrict__ xq,
                                              const float* __restrict__ W0,
                                              const float* __restrict__ W1,
                                              const float* __restrict__ W2,
                                              float* __restrict__ s0,
                                              float* __restrict__ s1,
                                              float* __restrict__ xqw) {
    int wid = (blockIdx.x * 256 + threadIdx.x) >> 6;   // one wave per row
    int l = threadIdx.x & 63;
    if (wid < BB * CC) {
        const float* r = xc + (size_t)wid * DD;
        float v = r[l] * W0[l] + r[l + 64] * W0[l + 64];
        #pragma unroll
        for (int off = 1; off < 64; off <<= 1) v += __shfl_xor(v, off, 64);
        if (l == 0) s0[wid] = v;
    } else {
        int rq = wid - BB * CC;                         // < B*Q
        const float* r = xq + (size_t)rq * DD;
        float a0 = r[l], a1 = r[l + 64];
        xqw[(size_t)rq * DD + l] = a0 * W2[l];
        xqw[(size_t)rq * DD + l + 64] = a1 * W2[l + 64];
        float v = a0 * W1[l] + a1 * W1[l + 64];
        #pragma unroll
        for (int off = 1; off < 64; off <<= 1) v += __shfl_xor(v, off, 64);
        if (l == 0) s1[rq] = v;
    }
}

// ---------------- k1: column softmax over c, A = S_T @ x_cont ----------------
// block = (b, group of 8 q).  grid = 64 * 32
#define QG 8
__global__ __launch_bounds__(256) void k1_colsm(const float* __restrict__ xc,
                                                const float* __restrict__ c_mask,
                                                const float* __restrict__ s0w,
                                                const float* __restrict__ xqw,
                                                float* __restrict__ Aout) {
    __shared__ float s_all[QG][CC + 1];     // scores [q][c]  (~32.8 KB)
    __shared__ float xc_t[64][DD + 1];      // x_cont tile    (~33 KB)
    __shared__ float xqw_s[QG][DD];         // 8 query rows   (4 KB)
    __shared__ float invl[QG];

    int b  = blockIdx.x >> 5;               // 32 q-groups per batch
    int qg = blockIdx.x & 31;
    int q0 = qg * QG;
    int t  = threadIdx.x;
    int w  = t >> 6, l = t & 63;

    #pragma unroll
    for (int i = 0; i < 4; i++) {
        int idx = t + 256 * i;
        xqw_s[idx >> 7][idx & 127] = xqw[(size_t)(b * QQ + q0) * DD + idx];
    }

    // ---- phase 1: scores for all c ----
    for (int ct = 0; ct < 16; ++ct) {
        __syncthreads();                    // covers xqw_s on iter 0, xc_t reuse after
        #pragma unroll
        for (int i = 0; i < 32; i++) {
            int idx = t + 256 * i;
            xc_t[idx >> 7][idx & 127] = xc[(size_t)(b * CC + ct * 64) * DD + idx];
        }
        __syncthreads();
        int c = ct * 64 + l;
        float base = s0w[b * CC + c] + NEGV * (1.0f - c_mask[b * CC + c]);
        int ql = w * 2;
        float a0 = 0.f, a1 = 0.f;
        #pragma unroll 8
        for (int d = 0; d < DD; ++d) {
            float xv = xc_t[l][d];
            a0 += xv * xqw_s[ql][d];
            a1 += xv * xqw_s[ql + 1][d];
        }
        s_all[ql][c]     = a0 + base;
        s_all[ql + 1][c] = a1 + base;
    }
    __syncthreads();

    // ---- phase 2: softmax over c (1024) per q ----
    int q = t >> 5, k = t & 31;             // 8 q-groups x 32 lanes
    float m = -3.0e38f;
    #pragma unroll 8
    for (int i = 0; i < 32; i++) m = fmaxf(m, s_all[q][k + 32 * i]);
    #pragma unroll
    for (int off = 1; off < 32; off <<= 1) m = fmaxf(m, __shfl_xor(m, off, 64));
    float sum = 0.f;
    #pragma unroll 8
    for (int i = 0; i < 32; i++) {
        int idx = k + 32 * i;
        float e = __expf(s_all[q][idx] - m);
        s_all[q][idx] = e;
        sum += e;
    }
    #pragma unroll
    for (int off = 1; off < 32; off <<= 1) sum += __shfl_xor(sum, off, 64);
    if (k == 0) invl[q] = 1.0f / sum;

    // ---- phase 3: A[q,d] = sum_c w[c] * xc[c,d] ----
    float acc[4] = {0.f, 0.f, 0.f, 0.f};
    for (int ct = 0; ct < 16; ++ct) {
        __syncthreads();
        #pragma unroll
        for (int i = 0; i < 32; i++) {
            int idx = t + 256 * i;
            xc_t[idx >> 7][idx & 127] = xc[(size_t)(b * CC + ct * 64) * DD + idx];
        }
        __syncthreads();
        for (int cc = 0; cc < 64; ++cc) {
            float wgt = s_all[q][ct * 64 + cc];
            #pragma unroll
            for (int j = 0; j < 4; j++) acc[j] += wgt * xc_t[cc][k + 32 * j];
        }
    }
    float il = invl[q];
    size_t basea = (size_t)(b * QQ + q0 + q) * DD;
    #pragma unroll
    for (int j = 0; j < 4; j++) Aout[basea + k + 32 * j] = acc[j] * il;
}

// ---------------- k2: row softmax over q, c2q, q2c, fused concat ----------------
// block = (b, group of 16 c).  grid = 64 * 64
#define CT2 16
__global__ __launch_bounds__(256) void k2_rowsm(const float* __restrict__ xc,
                                                const float* __restrict__ xq,
                                                const float* __restrict__ q_mask,
                                                const float* __restrict__ s1w,
                                                const float* __restrict__ xqw,
                                                const float* __restrict__ Aw,
                                                float* __restrict__ out) {
    __shared__ float s_al[CT2][QQ + 1];     // scores [c][q] (16.4 KB)
    __shared__ float xcl[CT2][DD + 1];      // this block's x_cont rows (8.25 KB)
    __shared__ float tile[64][DD + 1];      // staging (33 KB)
    __shared__ float invl[CT2];

    int b  = blockIdx.x >> 6;               // 64 c-groups per batch
    int cg = blockIdx.x & 63;
    int c0 = cg * CT2;
    int t  = threadIdx.x;
    int w  = t >> 6, l = t & 63;

    #pragma unroll
    for (int i = 0; i < 8; i++) {
        int idx = t + 256 * i;
        xcl[idx >> 7][idx & 127] = xc[(size_t)(b * CC + c0) * DD + idx];
    }

    // ---- phase 1: scores S[c][q] for q in 0..255 ----
    for (int qt = 0; qt < 4; ++qt) {
        __syncthreads();
        #pragma unroll
        for (int i = 0; i < 32; i++) {
            int idx = t + 256 * i;
            tile[idx >> 7][idx & 127] = xqw[(size_t)(b * QQ + qt * 64) * DD + idx];
        }
        __syncthreads();
        int qi = qt * 64 + l;
        float s1v = s1w[b * QQ + qi] + NEGV * (1.0f - q_mask[b * QQ + qi]);
        float a0 = 0.f, a1 = 0.f, a2 = 0.f, a3 = 0.f;
        #pragma unroll 8
        for (int d = 0; d < DD; ++d) {
            float tv = tile[l][d];
            a0 += tv * xcl[w * 4 + 0][d];
            a1 += tv * xcl[w * 4 + 1][d];
            a2 += tv * xcl[w * 4 + 2][d];
            a3 += tv * xcl[w * 4 + 3][d];
        }
        s_al[w * 4 + 0][qi] = a0 + s1v;
        s_al[w * 4 + 1][qi] = a1 + s1v;
        s_al[w * 4 + 2][qi] = a2 + s1v;
        s_al[w * 4 + 3][qi] = a3 + s1v;
    }
    __syncthreads();

    // ---- phase 2: softmax over q (256) per c ----
    int c = t >> 4, k = t & 15;             // 16 c-groups x 16 lanes
    float m = -3.0e38f;
    #pragma unroll 8
    for (int i = 0; i < 16; i++) m = fmaxf(m, s_al[c][k + 16 * i]);
    #pragma unroll
    for (int off = 1; off < 16; off <<= 1) m = fmaxf(m, __shfl_xor(m, off, 64));
    float sum = 0.f;
    #pragma unroll 8
    for (int i = 0; i < 16; i++) {
        int idx = k + 16 * i;
        float e = __expf(s_al[c][idx] - m);
        s_al[c][idx] = e;
        sum += e;
    }
    #pragma unroll
    for (int off = 1; off < 16; off <<= 1) sum += __shfl_xor(sum, off, 64);
    if (k == 0) invl[c] = 1.0f / sum;

    // ---- phase 3a: c2q = W @ x_ques ----
    float ac[8] = {0.f}, aq[8] = {0.f};
    for (int qt = 0; qt < 4; ++qt) {
        __syncthreads();
        #pragma unroll
        for (int i = 0; i < 32; i++) {
            int idx = t + 256 * i;
            tile[idx >> 7][idx & 127] = xq[(size_t)(b * QQ + qt * 64) * DD + idx];
        }
        __syncthreads();
        for (int ql = 0; ql < 64; ++ql) {
            float wgt = s_al[c][qt * 64 + ql];
            #pragma unroll
            for (int j = 0; j < 8; j++) ac[j] += wgt * tile[ql][k + 16 * j];
        }
    }
    // ---- phase 3b: q2c = W @ A ----
    for (int qt = 0; qt < 4; ++qt) {
        __syncthreads();
        #pragma unroll
        for (int i = 0; i < 32; i++) {
            int idx = t + 256 * i;
            tile[idx >> 7][idx & 127] = Aw[(size_t)(b * QQ + qt * 64) * DD + idx];
        }
        __syncthreads();
        for (int ql = 0; ql < 64; ++ql) {
            float wgt = s_al[c][qt * 64 + ql];
            #pragma unroll
            for (int j = 0; j < 8; j++) aq[j] += wgt * tile[ql][k + 16 * j];
        }
    }

    // ---- epilogue: concat([xc, c2q, xc*c2q, xc*q2c]) ----
    float il = invl[c];
    size_t ob = (size_t)(b * CC + c0 + c) * (4 * DD);
    #pragma unroll
    for (int j = 0; j < 8; j++) {
        int d = k + 16 * j;
        float xv  = xcl[c][d];
        float c2v = ac[j] * il;
        float q2v = aq[j] * il;
        out[ob + d]          = xv;
        out[ob + DD + d]     = c2v;
        out[ob + 2 * DD + d] = xv * c2v;
        out[ob + 3 * DD + d] = xv * q2v;
    }
}

extern "C" void kernel_launch(void* const* d_in, const int* in_sizes, int n_in,
                              void* d_out, int out_size, void* d_ws, size_t ws_size,
                              hipStream_t stream) {
    const float* x_cont = (const float*)d_in[0];
    const float* x_ques = (const float*)d_in[1];
    const float* c_mask = (const float*)d_in[2];
    const float* q_mask = (const float*)d_in[3];
    const float* W0     = (const float*)d_in[4];
    const float* W1     = (const float*)d_in[5];
    const float* W2     = (const float*)d_in[6];
    // bias (d_in[7]) cancels in both softmaxes and is never otherwise used.
    float* out = (float*)d_out;

    float* ws  = (float*)d_ws;
    float* s0  = ws;                                   // B*C      = 65536
    float* s1  = ws + BB * CC;                         // B*Q      = 16384
    float* xqw = s1 + BB * QQ;                         // B*Q*D    = 2097152
    float* A   = xqw + (size_t)BB * QQ * DD;           // B*Q*D    = 2097152

    int rows = BB * CC + BB * QQ;                      // 81920, /4 waves per block
    k0_pre<<<rows / 4, 256, 0, stream>>>(x_cont, x_ques, W0, W1, W2, s0, s1, xqw);
    k1_colsm<<<BB * (QQ / QG), 256, 0, stream>>>(x_cont, c_mask, s0, xqw, A);
    k2_rowsm<<<BB * (CC / CT2), 256, 0, stream>>>(x_cont, x_ques, q_mask, s1, xqw, A, out);
}

// Round 2
// 299.300 us; speedup vs baseline: 3.4844x; 3.4844x over previous
//
#include <hip/hip_runtime.h>
#include <math.h>

#define BB 64
#define CC 1024
#define QQ 256
#define DD 128
#define NEGV (-1.0e30f)

typedef short bf8 __attribute__((ext_vector_type(8)));
typedef short bf4 __attribute__((ext_vector_type(4)));
typedef short bf2 __attribute__((ext_vector_type(2)));
typedef float f4v __attribute__((ext_vector_type(4)));

__device__ __forceinline__ short f2bf(float f) {
    unsigned u = __builtin_bit_cast(unsigned, f);
    u += 0x7FFFu + ((u >> 16) & 1u);            // RNE
    return (short)(u >> 16);
}
__device__ __forceinline__ float bf2f(short s) {
    unsigned u = ((unsigned)(unsigned short)s) << 16;
    return __builtin_bit_cast(float, u);
}

// ---------------- k0a: s0, s1, xc_bf (row-major), xqw_bf (row-major) ----------------
__global__ __launch_bounds__(256) void k0_pre(const float* __restrict__ xc,
                                              const float* __restrict__ xq,
                                              const float* __restrict__ W0,
                                              const float* __restrict__ W1,
                                              const float* __restrict__ W2,
                                              float* __restrict__ s0,
                                              float* __restrict__ s1,
                                              short* __restrict__ xc_bf,
                                              short* __restrict__ xqw_bf) {
    int wid = (blockIdx.x * 256 + threadIdx.x) >> 6;
    int l = threadIdx.x & 63;
    if (wid < BB * CC) {
        const float2* r = (const float2*)(xc + (size_t)wid * DD);
        float2 v = r[l];
        float2 w0 = ((const float2*)W0)[l];
        bf2 o; o.x = f2bf(v.x); o.y = f2bf(v.y);
        *(bf2*)&xc_bf[(size_t)wid * DD + 2 * l] = o;
        float acc = v.x * w0.x + v.y * w0.y;
        #pragma unroll
        for (int off = 1; off < 64; off <<= 1) acc += __shfl_xor(acc, off, 64);
        if (l == 0) s0[wid] = acc;
    } else {
        int rq = wid - BB * CC;
        const float2* r = (const float2*)(xq + (size_t)rq * DD);
        float2 v = r[l];
        float2 w1 = ((const float2*)W1)[l];
        float2 w2 = ((const float2*)W2)[l];
        bf2 o; o.x = f2bf(v.x * w2.x); o.y = f2bf(v.y * w2.y);
        *(bf2*)&xqw_bf[(size_t)rq * DD + 2 * l] = o;
        float acc = v.x * w1.x + v.y * w1.y;
        #pragma unroll
        for (int off = 1; off < 64; off <<= 1) acc += __shfl_xor(acc, off, 64);
        if (l == 0) s1[rq] = acc;
    }
}

// ---------------- k0b: 64x64-tile transpose fp32 [R][Cn] -> bf16 [Cn][R], per batch ----------------
__global__ __launch_bounds__(256) void k0_transpose(const float* __restrict__ src,
                                                    short* __restrict__ dst,
                                                    int R, int Cn) {
    __shared__ float tile[64][65];
    int tiles_r = R >> 6, tiles_c = Cn >> 6;
    int per_b = tiles_r * tiles_c;
    int b = blockIdx.x / per_b;
    int rem = blockIdx.x - b * per_b;
    int rt = rem / tiles_c;
    int ct = rem - rt * tiles_c;
    int t = threadIdx.x;
    int c4 = t & 15, rr = t >> 4;
    const float* sb = src + (size_t)b * R * Cn;
    #pragma unroll
    for (int p = 0; p < 4; ++p) {
        int ro = rr + p * 16;
        float4 g = *(const float4*)&sb[(size_t)(rt * 64 + ro) * Cn + ct * 64 + c4 * 4];
        tile[ro][c4 * 4 + 0] = g.x; tile[ro][c4 * 4 + 1] = g.y;
        tile[ro][c4 * 4 + 2] = g.z; tile[ro][c4 * 4 + 3] = g.w;
    }
    __syncthreads();
    short* db = dst + (size_t)b * R * Cn;
    #pragma unroll
    for (int p = 0; p < 4; ++p) {
        int oc = rr + p * 16;
        bf4 o;
        #pragma unroll
        for (int i = 0; i < 4; ++i) o[i] = f2bf(tile[c4 * 4 + i][oc]);
        *(bf4*)&db[(size_t)(ct * 64 + oc) * R + rt * 64 + c4 * 4] = o;
    }
}

#define SCP 1032   // k1 score row stride (bf16): 2-way bank alias, 16B-aligned rows
#define XAP 136    // row-major tile stride
#define XTP 72     // transposed tile stride

// ---------------- k1: col softmax over c, AT[b][d][q] = (Wc^T @ xc)^T ----------------
// block = (b, 16 q).  grid = 64*16.
__global__ __launch_bounds__(256, 2) void k1_colsm(
        const short* __restrict__ xc_bf, const short* __restrict__ xcT_bf,
        const short* __restrict__ xqw_bf, const float* __restrict__ s0w,
        const float* __restrict__ c_mask, short* __restrict__ AT) {
    __shared__ __align__(16) short sc[16][SCP];          // 33.0 KB scores/weights [q][c]
    __shared__ __align__(16) short pool[64 * XAP + 16 * XAP]; // 21.8 KB staging union
    __shared__ float s0t[64];
    __shared__ float invl[16];
    short (*xa)[XAP]  = (short(*)[XAP])pool;             // phase A: xc tile [c][d]
    short (*xqs)[XAP] = (short(*)[XAP])(pool + 64 * XAP);// phase A: xqw rows [q][d]
    short (*xct)[XTP] = (short(*)[XTP])pool;             // phase C: xcT tile [d][c]

    int b = blockIdx.x >> 4, qt = blockIdx.x & 15, q0 = qt * 16;
    int t = threadIdx.x, w = t >> 6, l = t & 63;
    int quad = l >> 4, l16 = l & 15;

    {   // stage the block's 16 xqw rows
        int d8 = t & 15, q = t >> 4;
        *(bf8*)&xqs[q][d8 * 8] =
            *(const bf8*)&xqw_bf[(size_t)((b * QQ + q0 + q) * DD) + d8 * 8];
    }

    // ---- phase A: S[c][q] for all 1024 c (MFMA, M=c,N=q,K=d) ----
    for (int ct = 0; ct < 16; ++ct) {
        __syncthreads();
        {
            int d8 = t & 15, cr = t >> 4;
            #pragma unroll
            for (int p = 0; p < 4; ++p)
                *(bf8*)&xa[cr + p * 16][d8 * 8] =
                    *(const bf8*)&xc_bf[(size_t)((b * CC + ct * 64 + cr + p * 16) * DD) + d8 * 8];
            if (t < 64)
                s0t[t] = s0w[b * CC + ct * 64 + t] + NEGV * (1.0f - c_mask[b * CC + ct * 64 + t]);
        }
        __syncthreads();
        f4v acc = {0.f, 0.f, 0.f, 0.f};
        #pragma unroll
        for (int ks = 0; ks < 4; ++ks) {
            bf8 a = *(const bf8*)&xa[w * 16 + l16][ks * 32 + quad * 8];
            bf8 bb = *(const bf8*)&xqs[l16][ks * 32 + quad * 8];
            acc = __builtin_amdgcn_mfma_f32_16x16x32_bf16(a, bb, acc, 0, 0, 0);
        }
        bf4 ov;
        #pragma unroll
        for (int r = 0; r < 4; ++r) ov[r] = f2bf(acc[r] + s0t[w * 16 + quad * 4 + r]);
        *(bf4*)&sc[l16][ct * 64 + w * 16 + quad * 4] = ov;  // D: col=q=l16, row=c
    }
    __syncthreads();

    // ---- phase B: softmax over c per q ----
    {
        int q = t >> 4, k = t & 15;
        float m = -3.0e38f;
        #pragma unroll 8
        for (int i = 0; i < 64; ++i) m = fmaxf(m, bf2f(sc[q][k + 16 * i]));
        #pragma unroll
        for (int off = 1; off < 16; off <<= 1) m = fmaxf(m, __shfl_xor(m, off, 64));
        float sum = 0.f;
        #pragma unroll 8
        for (int i = 0; i < 64; ++i) {
            int idx = k + 16 * i;
            float e = __expf(bf2f(sc[q][idx]) - m);
            sc[q][idx] = f2bf(e);
            sum += e;
        }
        #pragma unroll
        for (int off = 1; off < 16; off <<= 1) sum += __shfl_xor(sum, off, 64);
        if (k == 0) invl[q] = 1.0f / sum;
    }

    // ---- phase C: AT (M=q, N=d, K=c); A-op = sc[q][c], B-op = xcT[d][c] ----
    f4v acc0 = {0.f, 0.f, 0.f, 0.f}, acc1 = {0.f, 0.f, 0.f, 0.f};
    for (int ct = 0; ct < 16; ++ct) {
        __syncthreads();
        {
            int c8 = t & 7, dr = t >> 3;
            #pragma unroll
            for (int p = 0; p < 4; ++p)
                *(bf8*)&xct[dr + p * 32][c8 * 8] =
                    *(const bf8*)&xcT_bf[(size_t)((b * DD + dr + p * 32) * CC) + ct * 64 + c8 * 8];
        }
        __syncthreads();
        #pragma unroll
        for (int ks = 0; ks < 2; ++ks) {
            bf8 a = *(const bf8*)&sc[l16][ct * 64 + ks * 32 + quad * 8];
            bf8 b0 = *(const bf8*)&xct[w * 32 + l16][ks * 32 + quad * 8];
            acc0 = __builtin_amdgcn_mfma_f32_16x16x32_bf16(a, b0, acc0, 0, 0, 0);
            bf8 b1 = *(const bf8*)&xct[w * 32 + 16 + l16][ks * 32 + quad * 8];
            acc1 = __builtin_amdgcn_mfma_f32_16x16x32_bf16(a, b1, acc1, 0, 0, 0);
        }
    }
    {
        bf4 o0, o1;
        #pragma unroll
        for (int r = 0; r < 4; ++r) {
            float il = invl[quad * 4 + r];
            o0[r] = f2bf(acc0[r] * il);
            o1[r] = f2bf(acc1[r] * il);
        }
        int d0 = w * 32 + l16;
        *(bf4*)&AT[(size_t)((b * DD + d0) * QQ) + q0 + quad * 4] = o0;
        *(bf4*)&AT[(size_t)((b * DD + d0 + 16) * QQ) + q0 + quad * 4] = o1;
    }
}

#define S2P 264    // k2 score row stride (bf16)

// ---------------- k2: row softmax over q, c2q / q2c GEMMs, fused concat ----------------
// block = (b, 32 c).  grid = 64*32.
__global__ __launch_bounds__(256, 2) void k2_rowsm(
        const float* __restrict__ xc, const short* __restrict__ xc_bf,
        const short* __restrict__ xqw_bf, const short* __restrict__ xqT_bf,
        const short* __restrict__ AT, const float* __restrict__ s1w,
        const float* __restrict__ q_mask, float* __restrict__ out) {
    __shared__ __align__(16) short sc2[32][S2P];         // 16.9 KB scores/weights [c][q]
    __shared__ __align__(16) short pool[32 * XAP + 64 * XAP]; // 26.1 KB staging union
    __shared__ float s1t[QQ];
    __shared__ float invl2[32];
    short (*xa2)[XAP] = (short(*)[XAP])pool;             // phase 1: xc rows [c][d]
    short (*xqt)[XAP] = (short(*)[XAP])(pool + 32 * XAP);// phase 1: xqw tile [q][d]
    short (*tT)[XTP]  = (short(*)[XTP])pool;             // phase 3: xqT/AT tile [d][q]

    int b = blockIdx.x >> 5, cb = blockIdx.x & 31, c0g = cb * 32;
    int t = threadIdx.x, w = t >> 6, l = t & 63;
    int quad = l >> 4, l16 = l & 15;

    {   // stage the block's 32 xc rows + masked s1
        int d8 = t & 15, cr = t >> 4;
        #pragma unroll
        for (int p = 0; p < 2; ++p)
            *(bf8*)&xa2[cr + p * 16][d8 * 8] =
                *(const bf8*)&xc_bf[(size_t)((b * CC + c0g + cr + p * 16) * DD) + d8 * 8];
        s1t[t] = s1w[b * QQ + t] + NEGV * (1.0f - q_mask[b * QQ + t]);
    }

    // ---- phase 1: S^T (M=q, N=c, K=d); A-op = xqw rows, B-op = xc rows ----
    for (int qt = 0; qt < 4; ++qt) {
        __syncthreads();
        {
            int d8 = t & 15, qr = t >> 4;
            #pragma unroll
            for (int p = 0; p < 4; ++p)
                *(bf8*)&xqt[qr + p * 16][d8 * 8] =
                    *(const bf8*)&xqw_bf[(size_t)((b * QQ + qt * 64 + qr + p * 16) * DD) + d8 * 8];
        }
        __syncthreads();
        f4v acc0 = {0.f, 0.f, 0.f, 0.f}, acc1 = {0.f, 0.f, 0.f, 0.f};
        #pragma unroll
        for (int ks = 0; ks < 4; ++ks) {
            bf8 a = *(const bf8*)&xqt[w * 16 + l16][ks * 32 + quad * 8];
            bf8 b0 = *(const bf8*)&xa2[l16][ks * 32 + quad * 8];
            acc0 = __builtin_amdgcn_mfma_f32_16x16x32_bf16(a, b0, acc0, 0, 0, 0);
            bf8 b1 = *(const bf8*)&xa2[16 + l16][ks * 32 + quad * 8];
            acc1 = __builtin_amdgcn_mfma_f32_16x16x32_bf16(a, b1, acc1, 0, 0, 0);
        }
        int qbase = qt * 64 + w * 16 + quad * 4;
        bf4 o0, o1;
        #pragma unroll
        for (int r = 0; r < 4; ++r) {
            float sv = s1t[qbase + r];
            o0[r] = f2bf(acc0[r] + sv);
            o1[r] = f2bf(acc1[r] + sv);
        }
        *(bf4*)&sc2[l16][qbase] = o0;        // D: col=c=l16, rows=q (packed along q)
        *(bf4*)&sc2[16 + l16][qbase] = o1;
    }
    __syncthreads();

    // ---- phase 2: softmax over q per c ----
    {
        int c = t >> 3, k = t & 7;
        float m = -3.0e38f;
        #pragma unroll 8
        for (int i = 0; i < 32; ++i) m = fmaxf(m, bf2f(sc2[c][k + 8 * i]));
        #pragma unroll
        for (int off = 1; off < 8; off <<= 1) m = fmaxf(m, __shfl_xor(m, off, 64));
        float sum = 0.f;
        #pragma unroll 8
        for (int i = 0; i < 32; ++i) {
            int idx = k + 8 * i;
            float e = __expf(bf2f(sc2[c][idx]) - m);
            sc2[c][idx] = f2bf(e);
            sum += e;
        }
        #pragma unroll
        for (int off = 1; off < 8; off <<= 1) sum += __shfl_xor(sum, off, 64);
        if (k == 0) invl2[c] = 1.0f / sum;
    }

    // ---- phase 3: c2q = W@xq, q2c = W@A (M=c, N=d, K=q) ----
    // wave w: c-block (w&1)*16, d-half (w>>1)*64 (4 n-frags each GEMM)
    int cb16 = (w & 1) * 16, dh = (w >> 1) * 64;
    f4v ac[4], aq[4];
    f4v zz = {0.f, 0.f, 0.f, 0.f};
    #pragma unroll
    for (int n = 0; n < 4; ++n) { ac[n] = zz; aq[n] = zz; }
    for (int qt = 0; qt < 4; ++qt) {
        __syncthreads();
        {
            int q8 = t & 7, dr = t >> 3;
            #pragma unroll
            for (int p = 0; p < 4; ++p)
                *(bf8*)&tT[dr + p * 32][q8 * 8] =
                    *(const bf8*)&xqT_bf[(size_t)((b * DD + dr + p * 32) * QQ) + qt * 64 + q8 * 8];
        }
        __syncthreads();
        #pragma unroll
        for (int ks = 0; ks < 2; ++ks) {
            bf8 a = *(const bf8*)&sc2[cb16 + l16][qt * 64 + ks * 32 + quad * 8];
            #pragma unroll
            for (int n = 0; n < 4; ++n) {
                bf8 bb = *(const bf8*)&tT[dh + n * 16 + l16][ks * 32 + quad * 8];
                ac[n] = __builtin_amdgcn_mfma_f32_16x16x32_bf16(a, bb, ac[n], 0, 0, 0);
            }
        }
    }
    for (int qt = 0; qt < 4; ++qt) {
        __syncthreads();
        {
            int q8 = t & 7, dr = t >> 3;
            #pragma unroll
            for (int p = 0; p < 4; ++p)
                *(bf8*)&tT[dr + p * 32][q8 * 8] =
                    *(const bf8*)&AT[(size_t)((b * DD + dr + p * 32) * QQ) + qt * 64 + q8 * 8];
        }
        __syncthreads();
        #pragma unroll
        for (int ks = 0; ks < 2; ++ks) {
            bf8 a = *(const bf8*)&sc2[cb16 + l16][qt * 64 + ks * 32 + quad * 8];
            #pragma unroll
            for (int n = 0; n < 4; ++n) {
                bf8 bb = *(const bf8*)&tT[dh + n * 16 + l16][ks * 32 + quad * 8];
                aq[n] = __builtin_amdgcn_mfma_f32_16x16x32_bf16(a, bb, aq[n], 0, 0, 0);
            }
        }
    }

    // ---- epilogue: concat([xc, c2q, xc*c2q, xc*q2c]) ----
    #pragma unroll
    for (int r = 0; r < 4; ++r) {
        int c = c0g + cb16 + quad * 4 + r;
        float il = invl2[cb16 + quad * 4 + r];
        const float* xrow = xc + (size_t)(b * CC + c) * DD;
        float* orow = out + (size_t)(b * CC + c) * (4 * DD);
        #pragma unroll
        for (int n = 0; n < 4; ++n) {
            int d = dh + n * 16 + l16;
            float xv = xrow[d];
            float c2v = ac[n][r] * il;
            float q2v = aq[n][r] * il;
            orow[d] = xv;
            orow[DD + d] = c2v;
            orow[2 * DD + d] = xv * c2v;
            orow[3 * DD + d] = xv * q2v;
        }
    }
}

extern "C" void kernel_launch(void* const* d_in, const int* in_sizes, int n_in,
                              void* d_out, int out_size, void* d_ws, size_t ws_size,
                              hipStream_t stream) {
    const float* x_cont = (const float*)d_in[0];
    const float* x_ques = (const float*)d_in[1];
    const float* c_mask = (const float*)d_in[2];
    const float* q_mask = (const float*)d_in[3];
    const float* W0     = (const float*)d_in[4];
    const float* W1     = (const float*)d_in[5];
    const float* W2     = (const float*)d_in[6];
    // bias cancels in both softmaxes.
    float* out = (float*)d_out;

    char* ws = (char*)d_ws;
    float* s0     = (float*)ws;  ws += (size_t)BB * CC * 4;
    float* s1     = (float*)ws;  ws += (size_t)BB * QQ * 4;
    short* xc_bf  = (short*)ws;  ws += (size_t)BB * CC * DD * 2;
    short* xqw_bf = (short*)ws;  ws += (size_t)BB * QQ * DD * 2;
    short* xcT_bf = (short*)ws;  ws += (size_t)BB * CC * DD * 2;
    short* xqT_bf = (short*)ws;  ws += (size_t)BB * QQ * DD * 2;
    short* AT     = (short*)ws;  // B*D*Q

    k0_pre<<<(BB * CC + BB * QQ) / 4, 256, 0, stream>>>(x_cont, x_ques, W0, W1, W2,
                                                        s0, s1, xc_bf, xqw_bf);
    k0_transpose<<<BB * 16 * 2, 256, 0, stream>>>(x_cont, xcT_bf, CC, DD);
    k0_transpose<<<BB * 4 * 2, 256, 0, stream>>>(x_ques, xqT_bf, QQ, DD);
    k1_colsm<<<BB * 16, 256, 0, stream>>>(xc_bf, xcT_bf, xqw_bf, s0, c_mask, AT);
    k2_rowsm<<<BB * 32, 256, 0, stream>>>(x_cont, xc_bf, xqw_bf, xqT_bf, AT, s1, q_mask, out);
}